// Round 1
// 1479.869 us; speedup vs baseline: 1.2376x; 1.2376x over previous
//
#include <hip/hip_runtime.h>
#include <hip/hip_bf16.h>

// MotionFormerBlock MI355X — Round 3: MFMA attention core.
// Pipeline: wprep×5, ln1 -> Q gemm, KV gemm -> attn core (MFMA) -> proj gemm(+res)
//           -> motion gemm -> ln2 -> fc1 gemm -> conv -> wprep(fc2) -> fc2 gemm(rmw)

#define NTOK 131072

using bf16x8 = __attribute__((ext_vector_type(8))) short;
using f32x4  = __attribute__((ext_vector_type(4))) float;

static __device__ __forceinline__ unsigned f2bfbits(float f) {
  __hip_bfloat16 h = __float2bfloat16(f);
  return (unsigned)*reinterpret_cast<unsigned short*>(&h);
}
static __device__ __forceinline__ float bfbits2f(unsigned short u) {
  return __uint_as_float(((unsigned)u) << 16);
}
static __device__ __forceinline__ void gld16(const void* g, void* l) {
  __builtin_amdgcn_global_load_lds(
      (const __attribute__((address_space(1))) void*)g,
      (__attribute__((address_space(3))) void*)l, 16, 0, 0);
}

// ---- weight prep: fp32 KxN -> bf16 NxK (transpose) ----
__global__ __launch_bounds__(256) void k_wt(const float* __restrict__ in,
    unsigned short* __restrict__ out, int K, int N) {
  int n = blockIdx.y * 256 + threadIdx.x;
  int k = blockIdx.x;
  if (n < N) out[(size_t)n * K + k] = (unsigned short)f2bfbits(in[(size_t)k * N + n]);
}

// ---- LN1: x fp32 -> bf16 ----
__global__ __launch_bounds__(256) void k_ln1(const float* __restrict__ x,
    const float* __restrict__ g, const float* __restrict__ b,
    unsigned short* __restrict__ o) {
  int lane = threadIdx.x & 63;
  size_t t = (size_t)blockIdx.x * 4 + (threadIdx.x >> 6);
  float4 v = ((const float4*)(x + t * 256))[lane];
  float s = v.x + v.y + v.z + v.w;
  float ss = v.x*v.x + v.y*v.y + v.z*v.z + v.w*v.w;
  #pragma unroll
  for (int m = 32; m; m >>= 1) { s += __shfl_xor(s, m, 64); ss += __shfl_xor(ss, m, 64); }
  float mean = s * (1.0f/256.0f);
  float var = ss * (1.0f/256.0f) - mean*mean;
  float rstd = rsqrtf(var + 1e-5f);
  float4 gv = ((const float4*)g)[lane], bv = ((const float4*)b)[lane];
  uint2 p;
  p.x = f2bfbits((v.x-mean)*rstd*gv.x + bv.x) | (f2bfbits((v.y-mean)*rstd*gv.y + bv.y) << 16);
  p.y = f2bfbits((v.z-mean)*rstd*gv.z + bv.z) | (f2bfbits((v.w-mean)*rstd*gv.w + bv.w) << 16);
  *(uint2*)(o + t * 256 + lane * 4) = p;
}

// ---- LN2: xout fp32 -> bf16 (same math, different src) ----
__global__ __launch_bounds__(256) void k_ln2(const float* __restrict__ x,
    const float* __restrict__ g, const float* __restrict__ b,
    unsigned short* __restrict__ o) {
  int lane = threadIdx.x & 63;
  size_t t = (size_t)blockIdx.x * 4 + (threadIdx.x >> 6);
  float4 v = ((const float4*)(x + t * 256))[lane];
  float s = v.x + v.y + v.z + v.w;
  float ss = v.x*v.x + v.y*v.y + v.z*v.z + v.w*v.w;
  #pragma unroll
  for (int m = 32; m; m >>= 1) { s += __shfl_xor(s, m, 64); ss += __shfl_xor(ss, m, 64); }
  float mean = s * (1.0f/256.0f);
  float var = ss * (1.0f/256.0f) - mean*mean;
  float rstd = rsqrtf(var + 1e-5f);
  float4 gv = ((const float4*)g)[lane], bv = ((const float4*)b)[lane];
  uint2 p;
  p.x = f2bfbits((v.x-mean)*rstd*gv.x + bv.x) | (f2bfbits((v.y-mean)*rstd*gv.y + bv.y) << 16);
  p.y = f2bfbits((v.z-mean)*rstd*gv.z + bv.z) | (f2bfbits((v.w-mean)*rstd*gv.w + bv.w) << 16);
  *(uint2*)(o + t * 256 + lane * 4) = p;
}

// ---- MFMA GEMM: C[M,N] = A[M,K]bf16 @ Bt[N,K]bf16^T, 128x128 tile ----
template<int EPI>
__global__ __launch_bounds__(256) void k_gemm(
    const unsigned short* __restrict__ A, const unsigned short* __restrict__ Bt,
    const float* __restrict__ bias, const unsigned short* __restrict__ resb,
    float* __restrict__ outf, unsigned short* __restrict__ outb, int K, int N) {
  __shared__ __attribute__((aligned(16))) unsigned short sA[128 * 32];
  __shared__ __attribute__((aligned(16))) unsigned short sB[128 * 32];
  const int tid = threadIdx.x;
  const int m0 = blockIdx.x << 7, n0 = blockIdx.y << 7;
  const int wid = tid >> 6, lane = tid & 63, quad = lane >> 4, ln = lane & 15;
  const int wm = (wid & 1) << 6, wn = (wid >> 1) << 6;

  const unsigned short* ga = A + (size_t)(m0 + (tid >> 2)) * K + (tid & 3) * 8;
  const unsigned short* gb = Bt + (size_t)(n0 + (tid >> 2)) * K + (tid & 3) * 8;
  unsigned short* la = sA + tid * 8;
  unsigned short* lb = sB + tid * 8;
  const size_t gstep = (size_t)64 * K;

  f32x4 acc[4][4];
  #pragma unroll
  for (int i = 0; i < 4; ++i)
    #pragma unroll
    for (int j = 0; j < 4; ++j) acc[i][j] = (f32x4)0.0f;

  for (int kt = 0; kt < K; kt += 32) {
    gld16(ga, la);            gld16(ga + gstep, la + 2048);
    gld16(gb, lb);            gld16(gb + gstep, lb + 2048);
    ga += 32; gb += 32;
    __syncthreads();
    bf16x8 afr[4], bfr[4];
    #pragma unroll
    for (int i = 0; i < 4; ++i) {
      afr[i] = *(const bf16x8*)(sA + (wm + i*16 + ln) * 32 + quad * 8);
      bfr[i] = *(const bf16x8*)(sB + (wn + i*16 + ln) * 32 + quad * 8);
    }
    #pragma unroll
    for (int i = 0; i < 4; ++i)
      #pragma unroll
      for (int j = 0; j < 4; ++j)
        acc[i][j] = __builtin_amdgcn_mfma_f32_16x16x32_bf16(afr[i], bfr[j], acc[i][j], 0, 0, 0);
    __syncthreads();
  }

  #pragma unroll
  for (int j = 0; j < 4; ++j) {
    int col = n0 + wn + j*16 + ln;
    float bv = bias[col];
    #pragma unroll
    for (int i = 0; i < 4; ++i) {
      int rowb = m0 + wm + i*16 + quad*4;
      #pragma unroll
      for (int r = 0; r < 4; ++r) {
        float v = acc[i][j][r] + bv;
        size_t off = (size_t)(rowb + r) * N + col;
        if (EPI == 0)      outb[off] = (unsigned short)f2bfbits(v);
        else if (EPI == 1) outf[off] = v + bfbits2f(resb[off]);
        else if (EPI == 2) outf[off] = v;
        else               outf[off] += v;
      }
    }
  }
}

// ---- attention core, MFMA version ----
// One (window, head) task per wave; 4 waves / 256-thr block; LDS wave-private,
// zero __syncthreads. Fragment layouts identical to k_gemm (verified).
//  S^T = mfma(Kfrag, Qfrag)  (A/B frags straight from global, row-major [tok][d])
//  softmax over keys: 16 in-lane + shfl_xor(16,32) across quads
//  P -> bf16, staged to LDS [64][72] (pad 8 => 2-way conflicts only)
//  AF^T = mfma(V^T, P), MF^T = mfma(CE^T, P) share P B-frags;
//  transposed D => r=0..3 are consecutive dims => packed 8B global stores.
__global__ __launch_bounds__(256) void k_attn3(
    const unsigned short* __restrict__ q, const unsigned short* __restrict__ kv,
    const float* __restrict__ cor, const float* __restrict__ Wce,
    const float* __restrict__ bce, unsigned short* __restrict__ af,
    unsigned short* __restrict__ mdiff) {
  // per-wave slice: Vt[32][72] (2304) + CEt[16][72] (1152) + P[64][72] (4608) = 8064 ush
  __shared__ __attribute__((aligned(16))) unsigned short lds[4 * 8064];  // 64512 B
  const int tid = threadIdx.x;
  const int wid = tid >> 6, lane = tid & 63;
  const int quad = lane >> 4, ln = lane & 15;
  unsigned short* Vt  = lds + wid * 8064;
  unsigned short* CEt = Vt + 2304;
  unsigned short* P   = Vt + 3456;

  const int task = blockIdx.x * 4 + wid;
  const int w = task >> 3;
  const int h = task & 7;
  const int hs = __builtin_amdgcn_readfirstlane(h);   // wave-uniform -> s_loads for Wce/bce
  const int b = w >> 8, widx = w & 255;
  const int base = b*16384 + (widx >> 4)*1024 + (widx & 15)*8;

  // ---- stage V^T and CE^T (lane = own token) ----
  const int ti  = base + ((lane >> 3) << 7) + (lane & 7);
  const int tpi = ti ^ 65536;
  {
    const unsigned short* vsrc = kv + (size_t)tpi*512 + 256 + hs*32;
    #pragma unroll
    for (int s = 0; s < 4; ++s) {
      bf16x8 vv = *(const bf16x8*)(vsrc + s*8);
      #pragma unroll
      for (int j = 0; j < 8; ++j) Vt[(s*8+j)*72 + lane] = (unsigned short)vv[j];
    }
    float2 cv = *(const float2*)(cor + (size_t)ti*2);
    #pragma unroll
    for (int d = 0; d < 16; ++d) {
      int c = hs*16 + d;
      float ce = cv.x*Wce[c] + cv.y*Wce[128+c] + bce[c];
      CEt[d*72 + lane] = (unsigned short)f2bfbits(ce);
    }
  }

  // ---- K (A-frag) and Q (B-frag) straight from global ----
  bf16x8 kf[4], qf[4];
  #pragma unroll
  for (int m = 0; m < 4; ++m) {
    int i = m*16 + ln;
    int t = base + ((i >> 3) << 7) + (i & 7);
    kf[m] = *(const bf16x8*)(kv + (size_t)(t ^ 65536)*512 + hs*32 + quad*8);
    qf[m] = *(const bf16x8*)(q  + (size_t)t*256          + hs*32 + quad*8);
  }

  // ---- S^T = K · Q^T : lane holds S^T[m*16+quad*4+r][n*16+ln] ----
  f32x4 sc[4][4];
  #pragma unroll
  for (int m = 0; m < 4; ++m)
    #pragma unroll
    for (int n = 0; n < 4; ++n) sc[m][n] = (f32x4)0.0f;
  #pragma unroll
  for (int m = 0; m < 4; ++m)
    #pragma unroll
    for (int n = 0; n < 4; ++n)
      sc[m][n] = __builtin_amdgcn_mfma_f32_16x16x32_bf16(kf[m], qf[n], sc[m][n], 0, 0, 0);

  // ---- softmax over keys (rows of S^T): 16 in-lane + quads via shfl(16,32) ----
  const float scale = 0.1767766952966369f;
  #pragma unroll
  for (int n = 0; n < 4; ++n) {
    float mx = -1e30f;
    #pragma unroll
    for (int m = 0; m < 4; ++m)
      #pragma unroll
      for (int r = 0; r < 4; ++r) mx = fmaxf(mx, sc[m][n][r]);
    mx = fmaxf(mx, __shfl_xor(mx, 16, 64));
    mx = fmaxf(mx, __shfl_xor(mx, 32, 64));
    mx *= scale;
    float sum = 0.f;
    #pragma unroll
    for (int m = 0; m < 4; ++m)
      #pragma unroll
      for (int r = 0; r < 4; ++r) {
        float e = __expf(sc[m][n][r]*scale - mx);
        sc[m][n][r] = e; sum += e;
      }
    sum += __shfl_xor(sum, 16, 64);
    sum += __shfl_xor(sum, 32, 64);
    float inv = 1.0f / sum;
    // write P[q = n*16+ln][k = m*16+quad*4 + r] packed 4xbf16 (8B)
    #pragma unroll
    for (int m = 0; m < 4; ++m) {
      uint2 pk;
      pk.x = f2bfbits(sc[m][n][0]*inv) | (f2bfbits(sc[m][n][1]*inv) << 16);
      pk.y = f2bfbits(sc[m][n][2]*inv) | (f2bfbits(sc[m][n][3]*inv) << 16);
      *(uint2*)(P + (n*16+ln)*72 + m*16 + quad*4) = pk;
    }
  }

  // ---- P B-frags (shared by PV and Pce) ----
  bf16x8 pf[4][2];
  #pragma unroll
  for (int n = 0; n < 4; ++n)
    #pragma unroll
    for (int k = 0; k < 2; ++k)
      pf[n][k] = *(const bf16x8*)(P + (n*16+ln)*72 + k*32 + quad*8);

  // ---- AF^T = V^T·P^T-style, MF^T = CE^T· ----
  f32x4 av[2][4], mc[4];
  #pragma unroll
  for (int n = 0; n < 4; ++n) { av[0][n] = (f32x4)0.0f; av[1][n] = (f32x4)0.0f; mc[n] = (f32x4)0.0f; }
  #pragma unroll
  for (int k = 0; k < 2; ++k) {
    bf16x8 va0 = *(const bf16x8*)(Vt  + (0  + ln)*72 + k*32 + quad*8);
    bf16x8 va1 = *(const bf16x8*)(Vt  + (16 + ln)*72 + k*32 + quad*8);
    bf16x8 ca  = *(const bf16x8*)(CEt + ln*72        + k*32 + quad*8);
    #pragma unroll
    for (int n = 0; n < 4; ++n) {
      av[0][n] = __builtin_amdgcn_mfma_f32_16x16x32_bf16(va0, pf[n][k], av[0][n], 0, 0, 0);
      av[1][n] = __builtin_amdgcn_mfma_f32_16x16x32_bf16(va1, pf[n][k], av[1][n], 0, 0, 0);
      mc[n]    = __builtin_amdgcn_mfma_f32_16x16x32_bf16(ca,  pf[n][k], mc[n],    0, 0, 0);
    }
  }

  // ---- epilogue: AF^T lane holds AF[q=n*16+ln][d=m*16+quad*4+r] -> pack r ----
  #pragma unroll
  for (int n = 0; n < 4; ++n) {
    int i = n*16 + ln;
    int t = base + ((i >> 3) << 7) + (i & 7);
    unsigned short* ao = af + (size_t)t*256 + hs*32;
    #pragma unroll
    for (int m = 0; m < 2; ++m) {
      uint2 pk;
      pk.x = f2bfbits(av[m][n][0]) | (f2bfbits(av[m][n][1]) << 16);
      pk.y = f2bfbits(av[m][n][2]) | (f2bfbits(av[m][n][3]) << 16);
      *(uint2*)(ao + m*16 + quad*4) = pk;
    }
    float c0 = bfbits2f(CEt[(quad*4+0)*72 + i]);
    float c1 = bfbits2f(CEt[(quad*4+1)*72 + i]);
    float c2 = bfbits2f(CEt[(quad*4+2)*72 + i]);
    float c3 = bfbits2f(CEt[(quad*4+3)*72 + i]);
    uint2 pm;
    pm.x = f2bfbits(mc[n][0]-c0) | (f2bfbits(mc[n][1]-c1) << 16);
    pm.y = f2bfbits(mc[n][2]-c2) | (f2bfbits(mc[n][3]-c3) << 16);
    *(uint2*)(mdiff + (size_t)t*128 + hs*16 + quad*4) = pm;
  }
}

// ---- depthwise 3x3 SAME + bias + exact gelu (bf16 in/out) ----
__global__ __launch_bounds__(256) void k_conv(const unsigned short* __restrict__ h1,
    const float* __restrict__ Wdw, const float* __restrict__ bdw,
    unsigned short* __restrict__ h2) {
  size_t e = (size_t)blockIdx.x * 256 + threadIdx.x;
  int t = (int)(e >> 8);
  int gch = (int)(e & 255) * 4;
  int b = t >> 14, tl = t & 16383;
  int row = tl >> 7, col = tl & 127;
  const float4 bb = *(const float4*)(bdw + gch);
  float a0 = bb.x, a1 = bb.y, a2 = bb.z, a3 = bb.w;
  #pragma unroll
  for (int kr = 0; kr < 3; ++kr) {
    int r2 = row + kr - 1;
    if ((unsigned)r2 > 127u) continue;
    #pragma unroll
    for (int kc = 0; kc < 3; ++kc) {
      int c2 = col + kc - 1;
      if ((unsigned)c2 > 127u) continue;
      const unsigned short* p = h1 + (((size_t)b*16384 + r2*128 + c2)*1024 + gch);
      uint2 raw = *(const uint2*)p;
      float x0 = __uint_as_float(raw.x << 16);
      float x1 = __uint_as_float(raw.x & 0xffff0000u);
      float x2 = __uint_as_float(raw.y << 16);
      float x3 = __uint_as_float(raw.y & 0xffff0000u);
      const float4 wv = *(const float4*)(Wdw + (kr*3 + kc)*1024 + gch);
      a0 += x0*wv.x; a1 += x1*wv.y; a2 += x2*wv.z; a3 += x3*wv.w;
    }
  }
  const float k = 0.70710678118654752440f;
  a0 = 0.5f*a0*(1.0f + erff(a0*k));
  a1 = 0.5f*a1*(1.0f + erff(a1*k));
  a2 = 0.5f*a2*(1.0f + erff(a2*k));
  a3 = 0.5f*a3*(1.0f + erff(a3*k));
  uint2 o;
  o.x = f2bfbits(a0) | (f2bfbits(a1) << 16);
  o.y = f2bfbits(a2) | (f2bfbits(a3) << 16);
  *(uint2*)(h2 + (size_t)t*1024 + gch) = o;
}

extern "C" void kernel_launch(void* const* d_in, const int* in_sizes, int n_in,
                              void* d_out, int out_size, void* d_ws, size_t ws_size,
                              hipStream_t stream) {
  const float* x     = (const float*)d_in[0];
  const float* cor   = (const float*)d_in[1];
  const float* g1    = (const float*)d_in[2];
  const float* b1    = (const float*)d_in[3];
  const float* Wq    = (const float*)d_in[4];
  const float* bq    = (const float*)d_in[5];
  const float* Wkv   = (const float*)d_in[6];
  const float* bkv   = (const float*)d_in[7];
  const float* Wproj = (const float*)d_in[8];
  const float* bproj = (const float*)d_in[9];
  const float* Wce   = (const float*)d_in[10];
  const float* bce   = (const float*)d_in[11];
  const float* Wmp   = (const float*)d_in[12];
  const float* bmp   = (const float*)d_in[13];
  const float* g2    = (const float*)d_in[14];
  const float* b2    = (const float*)d_in[15];
  const float* Wfc1  = (const float*)d_in[16];
  const float* bfc1  = (const float*)d_in[17];
  const float* Wdw   = (const float*)d_in[18];
  const float* bdw   = (const float*)d_in[19];
  const float* Wfc2  = (const float*)d_in[20];
  const float* bfc2  = (const float*)d_in[21];

  float* xout = (float*)d_out;
  float* mout = xout + (size_t)NTOK * 256;

  unsigned short* ws16   = (unsigned short*)d_ws;
  unsigned short* xnormb = ws16;                 // 33554432 el
  unsigned short* qb     = ws16 + 33554432;      // 33554432 el
  unsigned short* kvb    = ws16 + 67108864;      // 67108864 el
  unsigned short* afb    = ws16 + 134217728;     // 33554432 el
  unsigned short* mdiff  = ws16 + 167772160;     // 16777216 el
  unsigned short* xn2    = ws16 + 184549376;     // 33554432 el
  unsigned short* Wqt    = ws16 + 218103808;     // 65536
  unsigned short* Wkvt   = ws16 + 218169344;     // 131072
  unsigned short* Wprojt = ws16 + 218300416;     // 65536
  unsigned short* Wmpt   = ws16 + 218365952;     // 16384
  unsigned short* Wfc1t  = ws16 + 218382336;     // 262144 (ends 218644480)
  unsigned short* h1     = ws16;                 // 134217728 el
  unsigned short* h2     = ws16 + 134217728;     // 134217728 el
  unsigned short* Wfc2t  = ws16;                 // 262144 el (prepped after conv)

  k_wt<<<dim3(256, 1), 256, 0, stream>>>(Wq,    Wqt,    256, 256);
  k_wt<<<dim3(256, 2), 256, 0, stream>>>(Wkv,   Wkvt,   256, 512);
  k_wt<<<dim3(256, 1), 256, 0, stream>>>(Wproj, Wprojt, 256, 256);
  k_wt<<<dim3(128, 1), 256, 0, stream>>>(Wmp,   Wmpt,   128, 128);
  k_wt<<<dim3(256, 4), 256, 0, stream>>>(Wfc1,  Wfc1t,  256, 1024);
  k_ln1<<<dim3(NTOK/4), 256, 0, stream>>>(x, g1, b1, xnormb);

  k_gemm<0><<<dim3(1024, 2), 256, 0, stream>>>(xnormb, Wqt,  bq,  nullptr, nullptr, qb,  256, 256);
  k_gemm<0><<<dim3(1024, 4), 256, 0, stream>>>(xnormb, Wkvt, bkv, nullptr, nullptr, kvb, 256, 512);
  k_attn3<<<dim3(4096), 256, 0, stream>>>(qb, kvb, cor, Wce, bce, afb, mdiff);
  k_gemm<1><<<dim3(1024, 2), 256, 0, stream>>>(afb, Wprojt, bproj, xnormb, xout, nullptr, 256, 256);
  k_gemm<2><<<dim3(1024, 1), 256, 0, stream>>>(mdiff, Wmpt, bmp, nullptr, mout, nullptr, 128, 128);
  k_ln2<<<dim3(NTOK/4), 256, 0, stream>>>(xout, g2, b2, xn2);
  k_gemm<0><<<dim3(1024, 8), 256, 0, stream>>>(xn2, Wfc1t, bfc1, nullptr, nullptr, h1, 256, 1024);
  k_conv<<<dim3(NTOK), 256, 0, stream>>>(h1, Wdw, bdw, h2);
  k_wt<<<dim3(1024, 1), 256, 0, stream>>>(Wfc2, Wfc2t, 1024, 256);
  k_gemm<3><<<dim3(1024, 2), 256, 0, stream>>>(h2, Wfc2t, bfc2, nullptr, xout, nullptr, 1024, 256);
}

// Round 6
// 1356.903 us; speedup vs baseline: 1.3497x; 1.0906x over previous
//
#include <hip/hip_runtime.h>
#include <hip/hip_bf16.h>

// MotionFormerBlock MI355X — Round 4 (resubmit #4 after GPU acquisition timeouts):
// row-streaming depthwise conv.
// Pipeline: wprep×5, ln1 -> Q gemm, KV gemm -> attn core (MFMA) -> proj gemm(+res)
//           -> motion gemm -> ln2 -> fc1 gemm -> conv(row-stream) -> wprep(fc2) -> fc2 gemm(rmw)

#define NTOK 131072

using bf16x8 = __attribute__((ext_vector_type(8))) short;
using f32x4  = __attribute__((ext_vector_type(4))) float;

static __device__ __forceinline__ unsigned f2bfbits(float f) {
  __hip_bfloat16 h = __float2bfloat16(f);
  return (unsigned)*reinterpret_cast<unsigned short*>(&h);
}
static __device__ __forceinline__ float bfbits2f(unsigned short u) {
  return __uint_as_float(((unsigned)u) << 16);
}
static __device__ __forceinline__ void gld16(const void* g, void* l) {
  __builtin_amdgcn_global_load_lds(
      (const __attribute__((address_space(1))) void*)g,
      (__attribute__((address_space(3))) void*)l, 16, 0, 0);
}
static __device__ __forceinline__ float4 unpk4(uint2 r) {
  float4 f;
  f.x = __uint_as_float(r.x << 16);
  f.y = __uint_as_float(r.x & 0xffff0000u);
  f.z = __uint_as_float(r.y << 16);
  f.w = __uint_as_float(r.y & 0xffff0000u);
  return f;
}
static __device__ __forceinline__ void fma4(float4& a, const float4 w, const float4 x) {
  a.x = fmaf(w.x, x.x, a.x); a.y = fmaf(w.y, x.y, a.y);
  a.z = fmaf(w.z, x.z, a.z); a.w = fmaf(w.w, x.w, a.w);
}

// ---- weight prep: fp32 KxN -> bf16 NxK (transpose) ----
__global__ __launch_bounds__(256) void k_wt(const float* __restrict__ in,
    unsigned short* __restrict__ out, int K, int N) {
  int n = blockIdx.y * 256 + threadIdx.x;
  int k = blockIdx.x;
  if (n < N) out[(size_t)n * K + k] = (unsigned short)f2bfbits(in[(size_t)k * N + n]);
}

// ---- LN1: x fp32 -> bf16 ----
__global__ __launch_bounds__(256) void k_ln1(const float* __restrict__ x,
    const float* __restrict__ g, const float* __restrict__ b,
    unsigned short* __restrict__ o) {
  int lane = threadIdx.x & 63;
  size_t t = (size_t)blockIdx.x * 4 + (threadIdx.x >> 6);
  float4 v = ((const float4*)(x + t * 256))[lane];
  float s = v.x + v.y + v.z + v.w;
  float ss = v.x*v.x + v.y*v.y + v.z*v.z + v.w*v.w;
  #pragma unroll
  for (int m = 32; m; m >>= 1) { s += __shfl_xor(s, m, 64); ss += __shfl_xor(ss, m, 64); }
  float mean = s * (1.0f/256.0f);
  float var = ss * (1.0f/256.0f) - mean*mean;
  float rstd = rsqrtf(var + 1e-5f);
  float4 gv = ((const float4*)g)[lane], bv = ((const float4*)b)[lane];
  uint2 p;
  p.x = f2bfbits((v.x-mean)*rstd*gv.x + bv.x) | (f2bfbits((v.y-mean)*rstd*gv.y + bv.y) << 16);
  p.y = f2bfbits((v.z-mean)*rstd*gv.z + bv.z) | (f2bfbits((v.w-mean)*rstd*gv.w + bv.w) << 16);
  *(uint2*)(o + t * 256 + lane * 4) = p;
}

// ---- LN2: xout fp32 -> bf16 (same math, different src) ----
__global__ __launch_bounds__(256) void k_ln2(const float* __restrict__ x,
    const float* __restrict__ g, const float* __restrict__ b,
    unsigned short* __restrict__ o) {
  int lane = threadIdx.x & 63;
  size_t t = (size_t)blockIdx.x * 4 + (threadIdx.x >> 6);
  float4 v = ((const float4*)(x + t * 256))[lane];
  float s = v.x + v.y + v.z + v.w;
  float ss = v.x*v.x + v.y*v.y + v.z*v.z + v.w*v.w;
  #pragma unroll
  for (int m = 32; m; m >>= 1) { s += __shfl_xor(s, m, 64); ss += __shfl_xor(ss, m, 64); }
  float mean = s * (1.0f/256.0f);
  float var = ss * (1.0f/256.0f) - mean*mean;
  float rstd = rsqrtf(var + 1e-5f);
  float4 gv = ((const float4*)g)[lane], bv = ((const float4*)b)[lane];
  uint2 p;
  p.x = f2bfbits((v.x-mean)*rstd*gv.x + bv.x) | (f2bfbits((v.y-mean)*rstd*gv.y + bv.y) << 16);
  p.y = f2bfbits((v.z-mean)*rstd*gv.z + bv.z) | (f2bfbits((v.w-mean)*rstd*gv.w + bv.w) << 16);
  *(uint2*)(o + t * 256 + lane * 4) = p;
}

// ---- MFMA GEMM: C[M,N] = A[M,K]bf16 @ Bt[N,K]bf16^T, 128x128 tile ----
template<int EPI>
__global__ __launch_bounds__(256) void k_gemm(
    const unsigned short* __restrict__ A, const unsigned short* __restrict__ Bt,
    const float* __restrict__ bias, const unsigned short* __restrict__ resb,
    float* __restrict__ outf, unsigned short* __restrict__ outb, int K, int N) {
  __shared__ __attribute__((aligned(16))) unsigned short sA[128 * 32];
  __shared__ __attribute__((aligned(16))) unsigned short sB[128 * 32];
  const int tid = threadIdx.x;
  const int m0 = blockIdx.x << 7, n0 = blockIdx.y << 7;
  const int wid = tid >> 6, lane = tid & 63, quad = lane >> 4, ln = lane & 15;
  const int wm = (wid & 1) << 6, wn = (wid >> 1) << 6;

  const unsigned short* ga = A + (size_t)(m0 + (tid >> 2)) * K + (tid & 3) * 8;
  const unsigned short* gb = Bt + (size_t)(n0 + (tid >> 2)) * K + (tid & 3) * 8;
  unsigned short* la = sA + tid * 8;
  unsigned short* lb = sB + tid * 8;
  const size_t gstep = (size_t)64 * K;

  f32x4 acc[4][4];
  #pragma unroll
  for (int i = 0; i < 4; ++i)
    #pragma unroll
    for (int j = 0; j < 4; ++j) acc[i][j] = (f32x4)0.0f;

  for (int kt = 0; kt < K; kt += 32) {
    gld16(ga, la);            gld16(ga + gstep, la + 2048);
    gld16(gb, lb);            gld16(gb + gstep, lb + 2048);
    ga += 32; gb += 32;
    __syncthreads();
    bf16x8 afr[4], bfr[4];
    #pragma unroll
    for (int i = 0; i < 4; ++i) {
      afr[i] = *(const bf16x8*)(sA + (wm + i*16 + ln) * 32 + quad * 8);
      bfr[i] = *(const bf16x8*)(sB + (wn + i*16 + ln) * 32 + quad * 8);
    }
    #pragma unroll
    for (int i = 0; i < 4; ++i)
      #pragma unroll
      for (int j = 0; j < 4; ++j)
        acc[i][j] = __builtin_amdgcn_mfma_f32_16x16x32_bf16(afr[i], bfr[j], acc[i][j], 0, 0, 0);
    __syncthreads();
  }

  #pragma unroll
  for (int j = 0; j < 4; ++j) {
    int col = n0 + wn + j*16 + ln;
    float bv = bias[col];
    #pragma unroll
    for (int i = 0; i < 4; ++i) {
      int rowb = m0 + wm + i*16 + quad*4;
      #pragma unroll
      for (int r = 0; r < 4; ++r) {
        float v = acc[i][j][r] + bv;
        size_t off = (size_t)(rowb + r) * N + col;
        if (EPI == 0)      outb[off] = (unsigned short)f2bfbits(v);
        else if (EPI == 1) outf[off] = v + bfbits2f(resb[off]);
        else if (EPI == 2) outf[off] = v;
        else               outf[off] += v;
      }
    }
  }
}

// ---- attention core, MFMA version (unchanged from R3) ----
__global__ __launch_bounds__(256) void k_attn3(
    const unsigned short* __restrict__ q, const unsigned short* __restrict__ kv,
    const float* __restrict__ cor, const float* __restrict__ Wce,
    const float* __restrict__ bce, unsigned short* __restrict__ af,
    unsigned short* __restrict__ mdiff) {
  __shared__ __attribute__((aligned(16))) unsigned short lds[4 * 8064];  // 64512 B
  const int tid = threadIdx.x;
  const int wid = tid >> 6, lane = tid & 63;
  const int quad = lane >> 4, ln = lane & 15;
  unsigned short* Vt  = lds + wid * 8064;
  unsigned short* CEt = Vt + 2304;
  unsigned short* P   = Vt + 3456;

  const int task = blockIdx.x * 4 + wid;
  const int w = task >> 3;
  const int h = task & 7;
  const int hs = __builtin_amdgcn_readfirstlane(h);
  const int b = w >> 8, widx = w & 255;
  const int base = b*16384 + (widx >> 4)*1024 + (widx & 15)*8;

  const int ti  = base + ((lane >> 3) << 7) + (lane & 7);
  const int tpi = ti ^ 65536;
  {
    const unsigned short* vsrc = kv + (size_t)tpi*512 + 256 + hs*32;
    #pragma unroll
    for (int s = 0; s < 4; ++s) {
      bf16x8 vv = *(const bf16x8*)(vsrc + s*8);
      #pragma unroll
      for (int j = 0; j < 8; ++j) Vt[(s*8+j)*72 + lane] = (unsigned short)vv[j];
    }
    float2 cv = *(const float2*)(cor + (size_t)ti*2);
    #pragma unroll
    for (int d = 0; d < 16; ++d) {
      int c = hs*16 + d;
      float ce = cv.x*Wce[c] + cv.y*Wce[128+c] + bce[c];
      CEt[d*72 + lane] = (unsigned short)f2bfbits(ce);
    }
  }

  bf16x8 kf[4], qf[4];
  #pragma unroll
  for (int m = 0; m < 4; ++m) {
    int i = m*16 + ln;
    int t = base + ((i >> 3) << 7) + (i & 7);
    kf[m] = *(const bf16x8*)(kv + (size_t)(t ^ 65536)*512 + hs*32 + quad*8);
    qf[m] = *(const bf16x8*)(q  + (size_t)t*256          + hs*32 + quad*8);
  }

  f32x4 sc[4][4];
  #pragma unroll
  for (int m = 0; m < 4; ++m)
    #pragma unroll
    for (int n = 0; n < 4; ++n) sc[m][n] = (f32x4)0.0f;
  #pragma unroll
  for (int m = 0; m < 4; ++m)
    #pragma unroll
    for (int n = 0; n < 4; ++n)
      sc[m][n] = __builtin_amdgcn_mfma_f32_16x16x32_bf16(kf[m], qf[n], sc[m][n], 0, 0, 0);

  const float scale = 0.1767766952966369f;
  #pragma unroll
  for (int n = 0; n < 4; ++n) {
    float mx = -1e30f;
    #pragma unroll
    for (int m = 0; m < 4; ++m)
      #pragma unroll
      for (int r = 0; r < 4; ++r) mx = fmaxf(mx, sc[m][n][r]);
    mx = fmaxf(mx, __shfl_xor(mx, 16, 64));
    mx = fmaxf(mx, __shfl_xor(mx, 32, 64));
    mx *= scale;
    float sum = 0.f;
    #pragma unroll
    for (int m = 0; m < 4; ++m)
      #pragma unroll
      for (int r = 0; r < 4; ++r) {
        float e = __expf(sc[m][n][r]*scale - mx);
        sc[m][n][r] = e; sum += e;
      }
    sum += __shfl_xor(sum, 16, 64);
    sum += __shfl_xor(sum, 32, 64);
    float inv = 1.0f / sum;
    #pragma unroll
    for (int m = 0; m < 4; ++m) {
      uint2 pk;
      pk.x = f2bfbits(sc[m][n][0]*inv) | (f2bfbits(sc[m][n][1]*inv) << 16);
      pk.y = f2bfbits(sc[m][n][2]*inv) | (f2bfbits(sc[m][n][3]*inv) << 16);
      *(uint2*)(P + (n*16+ln)*72 + m*16 + quad*4) = pk;
    }
  }

  bf16x8 pf[4][2];
  #pragma unroll
  for (int n = 0; n < 4; ++n)
    #pragma unroll
    for (int k = 0; k < 2; ++k)
      pf[n][k] = *(const bf16x8*)(P + (n*16+ln)*72 + k*32 + quad*8);

  f32x4 av[2][4], mc[4];
  #pragma unroll
  for (int n = 0; n < 4; ++n) { av[0][n] = (f32x4)0.0f; av[1][n] = (f32x4)0.0f; mc[n] = (f32x4)0.0f; }
  #pragma unroll
  for (int k = 0; k < 2; ++k) {
    bf16x8 va0 = *(const bf16x8*)(Vt  + (0  + ln)*72 + k*32 + quad*8);
    bf16x8 va1 = *(const bf16x8*)(Vt  + (16 + ln)*72 + k*32 + quad*8);
    bf16x8 ca  = *(const bf16x8*)(CEt + ln*72        + k*32 + quad*8);
    #pragma unroll
    for (int n = 0; n < 4; ++n) {
      av[0][n] = __builtin_amdgcn_mfma_f32_16x16x32_bf16(va0, pf[n][k], av[0][n], 0, 0, 0);
      av[1][n] = __builtin_amdgcn_mfma_f32_16x16x32_bf16(va1, pf[n][k], av[1][n], 0, 0, 0);
      mc[n]    = __builtin_amdgcn_mfma_f32_16x16x32_bf16(ca,  pf[n][k], mc[n],    0, 0, 0);
    }
  }

  #pragma unroll
  for (int n = 0; n < 4; ++n) {
    int i = n*16 + ln;
    int t = base + ((i >> 3) << 7) + (i & 7);
    unsigned short* ao = af + (size_t)t*256 + hs*32;
    #pragma unroll
    for (int m = 0; m < 2; ++m) {
      uint2 pk;
      pk.x = f2bfbits(av[m][n][0]) | (f2bfbits(av[m][n][1]) << 16);
      pk.y = f2bfbits(av[m][n][2]) | (f2bfbits(av[m][n][3]) << 16);
      *(uint2*)(ao + m*16 + quad*4) = pk;
    }
    float c0 = bfbits2f(CEt[(quad*4+0)*72 + i]);
    float c1 = bfbits2f(CEt[(quad*4+1)*72 + i]);
    float c2 = bfbits2f(CEt[(quad*4+2)*72 + i]);
    float c3 = bfbits2f(CEt[(quad*4+3)*72 + i]);
    uint2 pm;
    pm.x = f2bfbits(mc[n][0]-c0) | (f2bfbits(mc[n][1]-c1) << 16);
    pm.y = f2bfbits(mc[n][2]-c2) | (f2bfbits(mc[n][3]-c3) << 16);
    *(uint2*)(mdiff + (size_t)t*128 + hs*16 + quad*4) = pm;
  }
}

// ---- depthwise 3x3 SAME + bias + exact gelu, row-streaming ----
// Block = 1024 channels of one column × one 8-row strip.
// Per thread (4 ch): 9 weight taps in VGPRs, stream 10 input rows (3 uint2 each),
// 8 float4 accumulators, fully static indexing (unrolled dr loop).
__global__ __launch_bounds__(256) void k_conv(const unsigned short* __restrict__ h1,
    const float* __restrict__ Wdw, const float* __restrict__ bdw,
    unsigned short* __restrict__ h2) {
  const int blk = blockIdx.x;
  const int c  = blk & 127;              // column
  const int r0 = ((blk >> 7) & 15) << 3; // row strip base (8 rows)
  const int b  = blk >> 11;              // batch
  const int gch = threadIdx.x << 2;      // 4 channels per thread

  float4 w[3][3];
  #pragma unroll
  for (int kr = 0; kr < 3; ++kr)
    #pragma unroll
    for (int kc = 0; kc < 3; ++kc)
      w[kr][kc] = *(const float4*)(Wdw + (kr*3 + kc)*1024 + gch);
  const float4 bb = *(const float4*)(bdw + gch);

  float4 acc[8];
  #pragma unroll
  for (int i = 0; i < 8; ++i) acc[i] = bb;

  const bool cok0 = (c > 0), cok2 = (c < 127);
  const float4 zf = make_float4(0.f, 0.f, 0.f, 0.f);

  #pragma unroll
  for (int dr = -1; dr <= 8; ++dr) {
    const int ir = r0 + dr;
    float4 in0 = zf, in1 = zf, in2 = zf;
    if ((unsigned)ir <= 127u) {            // block-uniform
      const unsigned short* p = h1 + (((size_t)(b*128 + ir)*128 + c) << 10) + gch;
      in1 = unpk4(*(const uint2*)p);
      if (cok0) in0 = unpk4(*(const uint2*)(p - 1024));
      if (cok2) in2 = unpk4(*(const uint2*)(p + 1024));
    }
    // input row ir contributes: out dr-1 (kr=2), out dr (kr=1), out dr+1 (kr=0)
    if (dr - 1 >= 0 && dr - 1 <= 7) {
      fma4(acc[dr-1], w[2][0], in0); fma4(acc[dr-1], w[2][1], in1); fma4(acc[dr-1], w[2][2], in2);
    }
    if (dr >= 0 && dr <= 7) {
      fma4(acc[dr],   w[1][0], in0); fma4(acc[dr],   w[1][1], in1); fma4(acc[dr],   w[1][2], in2);
    }
    if (dr + 1 >= 0 && dr + 1 <= 7) {
      fma4(acc[dr+1], w[0][0], in0); fma4(acc[dr+1], w[0][1], in1); fma4(acc[dr+1], w[0][2], in2);
    }
  }

  const float kk = 0.70710678118654752440f;
  #pragma unroll
  for (int odr = 0; odr < 8; ++odr) {
    float4 a = acc[odr];
    a.x = 0.5f*a.x*(1.0f + erff(a.x*kk));
    a.y = 0.5f*a.y*(1.0f + erff(a.y*kk));
    a.z = 0.5f*a.z*(1.0f + erff(a.z*kk));
    a.w = 0.5f*a.w*(1.0f + erff(a.w*kk));
    uint2 o;
    o.x = f2bfbits(a.x) | (f2bfbits(a.y) << 16);
    o.y = f2bfbits(a.z) | (f2bfbits(a.w) << 16);
    *(uint2*)(h2 + (((size_t)(b*128 + r0 + odr)*128 + c) << 10) + gch) = o;
  }
}

extern "C" void kernel_launch(void* const* d_in, const int* in_sizes, int n_in,
                              void* d_out, int out_size, void* d_ws, size_t ws_size,
                              hipStream_t stream) {
  const float* x     = (const float*)d_in[0];
  const float* cor   = (const float*)d_in[1];
  const float* g1    = (const float*)d_in[2];
  const float* b1    = (const float*)d_in[3];
  const float* Wq    = (const float*)d_in[4];
  const float* bq    = (const float*)d_in[5];
  const float* Wkv   = (const float*)d_in[6];
  const float* bkv   = (const float*)d_in[7];
  const float* Wproj = (const float*)d_in[8];
  const float* bproj = (const float*)d_in[9];
  const float* Wce   = (const float*)d_in[10];
  const float* bce   = (const float*)d_in[11];
  const float* Wmp   = (const float*)d_in[12];
  const float* bmp   = (const float*)d_in[13];
  const float* g2    = (const float*)d_in[14];
  const float* b2    = (const float*)d_in[15];
  const float* Wfc1  = (const float*)d_in[16];
  const float* bfc1  = (const float*)d_in[17];
  const float* Wdw   = (const float*)d_in[18];
  const float* bdw   = (const float*)d_in[19];
  const float* Wfc2  = (const float*)d_in[20];
  const float* bfc2  = (const float*)d_in[21];

  float* xout = (float*)d_out;
  float* mout = xout + (size_t)NTOK * 256;

  unsigned short* ws16   = (unsigned short*)d_ws;
  unsigned short* xnormb = ws16;                 // 33554432 el
  unsigned short* qb     = ws16 + 33554432;      // 33554432 el
  unsigned short* kvb    = ws16 + 67108864;      // 67108864 el
  unsigned short* afb    = ws16 + 134217728;     // 33554432 el
  unsigned short* mdiff  = ws16 + 167772160;     // 16777216 el
  unsigned short* xn2    = ws16 + 184549376;     // 33554432 el
  unsigned short* Wqt    = ws16 + 218103808;     // 65536
  unsigned short* Wkvt   = ws16 + 218169344;     // 131072
  unsigned short* Wprojt = ws16 + 218300416;     // 65536
  unsigned short* Wmpt   = ws16 + 218365952;     // 16384
  unsigned short* Wfc1t  = ws16 + 218382336;     // 262144 (ends 218644480)
  unsigned short* h1     = ws16;                 // 134217728 el
  unsigned short* h2     = ws16 + 134217728;     // 134217728 el
  unsigned short* Wfc2t  = ws16;                 // 262144 el (prepped after conv)

  k_wt<<<dim3(256, 1), 256, 0, stream>>>(Wq,    Wqt,    256, 256);
  k_wt<<<dim3(256, 2), 256, 0, stream>>>(Wkv,   Wkvt,   256, 512);
  k_wt<<<dim3(256, 1), 256, 0, stream>>>(Wproj, Wprojt, 256, 256);
  k_wt<<<dim3(128, 1), 256, 0, stream>>>(Wmp,   Wmpt,   128, 128);
  k_wt<<<dim3(256, 4), 256, 0, stream>>>(Wfc1,  Wfc1t,  256, 1024);
  k_ln1<<<dim3(NTOK/4), 256, 0, stream>>>(x, g1, b1, xnormb);

  k_gemm<0><<<dim3(1024, 2), 256, 0, stream>>>(xnormb, Wqt,  bq,  nullptr, nullptr, qb,  256, 256);
  k_gemm<0><<<dim3(1024, 4), 256, 0, stream>>>(xnormb, Wkvt, bkv, nullptr, nullptr, kvb, 256, 512);
  k_attn3<<<dim3(4096), 256, 0, stream>>>(qb, kvb, cor, Wce, bce, afb, mdiff);
  k_gemm<1><<<dim3(1024, 2), 256, 0, stream>>>(afb, Wprojt, bproj, xnormb, xout, nullptr, 256, 256);
  k_gemm<2><<<dim3(1024, 1), 256, 0, stream>>>(mdiff, Wmpt, bmp, nullptr, mout, nullptr, 128, 128);
  k_ln2<<<dim3(NTOK/4), 256, 0, stream>>>(xout, g2, b2, xn2);
  k_gemm<0><<<dim3(1024, 8), 256, 0, stream>>>(xn2, Wfc1t, bfc1, nullptr, nullptr, h1, 256, 1024);
  k_conv<<<dim3(16384), 256, 0, stream>>>(h1, Wdw, bdw, h2);
  k_wt<<<dim3(1024, 1), 256, 0, stream>>>(Wfc2, Wfc2t, 1024, 256);
  k_gemm<3><<<dim3(1024, 2), 256, 0, stream>>>(h2, Wfc2t, bfc2, nullptr, xout, nullptr, 1024, 256);
}

// Round 10
// 1248.797 us; speedup vs baseline: 1.4666x; 1.0866x over previous
//
#include <hip/hip_runtime.h>
#include <hip/hip_bf16.h>

// MotionFormerBlock MI355X — Round 5 (resubmit #3 after GPU acquisition timeouts):
// branch-free prefetched depthwise conv.
// k_conv: 4-row strips, 18 unconditional prefetched loads (interior path),
// column edges via weight-zeroing + address clamp, row edges via specialized path.

#define NTOK 131072

using bf16x8 = __attribute__((ext_vector_type(8))) short;
using f32x4  = __attribute__((ext_vector_type(4))) float;

static __device__ __forceinline__ unsigned f2bfbits(float f) {
  __hip_bfloat16 h = __float2bfloat16(f);
  return (unsigned)*reinterpret_cast<unsigned short*>(&h);
}
static __device__ __forceinline__ float bfbits2f(unsigned short u) {
  return __uint_as_float(((unsigned)u) << 16);
}
static __device__ __forceinline__ void gld16(const void* g, void* l) {
  __builtin_amdgcn_global_load_lds(
      (const __attribute__((address_space(1))) void*)g,
      (__attribute__((address_space(3))) void*)l, 16, 0, 0);
}
static __device__ __forceinline__ float4 unpk4(uint2 r) {
  float4 f;
  f.x = __uint_as_float(r.x << 16);
  f.y = __uint_as_float(r.x & 0xffff0000u);
  f.z = __uint_as_float(r.y << 16);
  f.w = __uint_as_float(r.y & 0xffff0000u);
  return f;
}
static __device__ __forceinline__ void fma4(float4& a, const float4 w, const float4 x) {
  a.x = fmaf(w.x, x.x, a.x); a.y = fmaf(w.y, x.y, a.y);
  a.z = fmaf(w.z, x.z, a.z); a.w = fmaf(w.w, x.w, a.w);
}

// ---- weight prep: fp32 KxN -> bf16 NxK (transpose) ----
__global__ __launch_bounds__(256) void k_wt(const float* __restrict__ in,
    unsigned short* __restrict__ out, int K, int N) {
  int n = blockIdx.y * 256 + threadIdx.x;
  int k = blockIdx.x;
  if (n < N) out[(size_t)n * K + k] = (unsigned short)f2bfbits(in[(size_t)k * N + n]);
}

// ---- LN1: x fp32 -> bf16 ----
__global__ __launch_bounds__(256) void k_ln1(const float* __restrict__ x,
    const float* __restrict__ g, const float* __restrict__ b,
    unsigned short* __restrict__ o) {
  int lane = threadIdx.x & 63;
  size_t t = (size_t)blockIdx.x * 4 + (threadIdx.x >> 6);
  float4 v = ((const float4*)(x + t * 256))[lane];
  float s = v.x + v.y + v.z + v.w;
  float ss = v.x*v.x + v.y*v.y + v.z*v.z + v.w*v.w;
  #pragma unroll
  for (int m = 32; m; m >>= 1) { s += __shfl_xor(s, m, 64); ss += __shfl_xor(ss, m, 64); }
  float mean = s * (1.0f/256.0f);
  float var = ss * (1.0f/256.0f) - mean*mean;
  float rstd = rsqrtf(var + 1e-5f);
  float4 gv = ((const float4*)g)[lane], bv = ((const float4*)b)[lane];
  uint2 p;
  p.x = f2bfbits((v.x-mean)*rstd*gv.x + bv.x) | (f2bfbits((v.y-mean)*rstd*gv.y + bv.y) << 16);
  p.y = f2bfbits((v.z-mean)*rstd*gv.z + bv.z) | (f2bfbits((v.w-mean)*rstd*gv.w + bv.w) << 16);
  *(uint2*)(o + t * 256 + lane * 4) = p;
}

// ---- LN2: xout fp32 -> bf16 (same math, different src) ----
__global__ __launch_bounds__(256) void k_ln2(const float* __restrict__ x,
    const float* __restrict__ g, const float* __restrict__ b,
    unsigned short* __restrict__ o) {
  int lane = threadIdx.x & 63;
  size_t t = (size_t)blockIdx.x * 4 + (threadIdx.x >> 6);
  float4 v = ((const float4*)(x + t * 256))[lane];
  float s = v.x + v.y + v.z + v.w;
  float ss = v.x*v.x + v.y*v.y + v.z*v.z + v.w*v.w;
  #pragma unroll
  for (int m = 32; m; m >>= 1) { s += __shfl_xor(s, m, 64); ss += __shfl_xor(ss, m, 64); }
  float mean = s * (1.0f/256.0f);
  float var = ss * (1.0f/256.0f) - mean*mean;
  float rstd = rsqrtf(var + 1e-5f);
  float4 gv = ((const float4*)g)[lane], bv = ((const float4*)b)[lane];
  uint2 p;
  p.x = f2bfbits((v.x-mean)*rstd*gv.x + bv.x) | (f2bfbits((v.y-mean)*rstd*gv.y + bv.y) << 16);
  p.y = f2bfbits((v.z-mean)*rstd*gv.z + bv.z) | (f2bfbits((v.w-mean)*rstd*gv.w + bv.w) << 16);
  *(uint2*)(o + t * 256 + lane * 4) = p;
}

// ---- MFMA GEMM: C[M,N] = A[M,K]bf16 @ Bt[N,K]bf16^T, 128x128 tile ----
template<int EPI>
__global__ __launch_bounds__(256) void k_gemm(
    const unsigned short* __restrict__ A, const unsigned short* __restrict__ Bt,
    const float* __restrict__ bias, const unsigned short* __restrict__ resb,
    float* __restrict__ outf, unsigned short* __restrict__ outb, int K, int N) {
  __shared__ __attribute__((aligned(16))) unsigned short sA[128 * 32];
  __shared__ __attribute__((aligned(16))) unsigned short sB[128 * 32];
  const int tid = threadIdx.x;
  const int m0 = blockIdx.x << 7, n0 = blockIdx.y << 7;
  const int wid = tid >> 6, lane = tid & 63, quad = lane >> 4, ln = lane & 15;
  const int wm = (wid & 1) << 6, wn = (wid >> 1) << 6;

  const unsigned short* ga = A + (size_t)(m0 + (tid >> 2)) * K + (tid & 3) * 8;
  const unsigned short* gb = Bt + (size_t)(n0 + (tid >> 2)) * K + (tid & 3) * 8;
  unsigned short* la = sA + tid * 8;
  unsigned short* lb = sB + tid * 8;
  const size_t gstep = (size_t)64 * K;

  f32x4 acc[4][4];
  #pragma unroll
  for (int i = 0; i < 4; ++i)
    #pragma unroll
    for (int j = 0; j < 4; ++j) acc[i][j] = (f32x4)0.0f;

  for (int kt = 0; kt < K; kt += 32) {
    gld16(ga, la);            gld16(ga + gstep, la + 2048);
    gld16(gb, lb);            gld16(gb + gstep, lb + 2048);
    ga += 32; gb += 32;
    __syncthreads();
    bf16x8 afr[4], bfr[4];
    #pragma unroll
    for (int i = 0; i < 4; ++i) {
      afr[i] = *(const bf16x8*)(sA + (wm + i*16 + ln) * 32 + quad * 8);
      bfr[i] = *(const bf16x8*)(sB + (wn + i*16 + ln) * 32 + quad * 8);
    }
    #pragma unroll
    for (int i = 0; i < 4; ++i)
      #pragma unroll
      for (int j = 0; j < 4; ++j)
        acc[i][j] = __builtin_amdgcn_mfma_f32_16x16x32_bf16(afr[i], bfr[j], acc[i][j], 0, 0, 0);
    __syncthreads();
  }

  #pragma unroll
  for (int j = 0; j < 4; ++j) {
    int col = n0 + wn + j*16 + ln;
    float bv = bias[col];
    #pragma unroll
    for (int i = 0; i < 4; ++i) {
      int rowb = m0 + wm + i*16 + quad*4;
      #pragma unroll
      for (int r = 0; r < 4; ++r) {
        float v = acc[i][j][r] + bv;
        size_t off = (size_t)(rowb + r) * N + col;
        if (EPI == 0)      outb[off] = (unsigned short)f2bfbits(v);
        else if (EPI == 1) outf[off] = v + bfbits2f(resb[off]);
        else if (EPI == 2) outf[off] = v;
        else               outf[off] += v;
      }
    }
  }
}

// ---- attention core, MFMA version (unchanged from R3) ----
__global__ __launch_bounds__(256) void k_attn3(
    const unsigned short* __restrict__ q, const unsigned short* __restrict__ kv,
    const float* __restrict__ cor, const float* __restrict__ Wce,
    const float* __restrict__ bce, unsigned short* __restrict__ af,
    unsigned short* __restrict__ mdiff) {
  __shared__ __attribute__((aligned(16))) unsigned short lds[4 * 8064];  // 64512 B
  const int tid = threadIdx.x;
  const int wid = tid >> 6, lane = tid & 63;
  const int quad = lane >> 4, ln = lane & 15;
  unsigned short* Vt  = lds + wid * 8064;
  unsigned short* CEt = Vt + 2304;
  unsigned short* P   = Vt + 3456;

  const int task = blockIdx.x * 4 + wid;
  const int w = task >> 3;
  const int h = task & 7;
  const int hs = __builtin_amdgcn_readfirstlane(h);
  const int b = w >> 8, widx = w & 255;
  const int base = b*16384 + (widx >> 4)*1024 + (widx & 15)*8;

  const int ti  = base + ((lane >> 3) << 7) + (lane & 7);
  const int tpi = ti ^ 65536;
  {
    const unsigned short* vsrc = kv + (size_t)tpi*512 + 256 + hs*32;
    #pragma unroll
    for (int s = 0; s < 4; ++s) {
      bf16x8 vv = *(const bf16x8*)(vsrc + s*8);
      #pragma unroll
      for (int j = 0; j < 8; ++j) Vt[(s*8+j)*72 + lane] = (unsigned short)vv[j];
    }
    float2 cv = *(const float2*)(cor + (size_t)ti*2);
    #pragma unroll
    for (int d = 0; d < 16; ++d) {
      int c = hs*16 + d;
      float ce = cv.x*Wce[c] + cv.y*Wce[128+c] + bce[c];
      CEt[d*72 + lane] = (unsigned short)f2bfbits(ce);
    }
  }

  bf16x8 kf[4], qf[4];
  #pragma unroll
  for (int m = 0; m < 4; ++m) {
    int i = m*16 + ln;
    int t = base + ((i >> 3) << 7) + (i & 7);
    kf[m] = *(const bf16x8*)(kv + (size_t)(t ^ 65536)*512 + hs*32 + quad*8);
    qf[m] = *(const bf16x8*)(q  + (size_t)t*256          + hs*32 + quad*8);
  }

  f32x4 sc[4][4];
  #pragma unroll
  for (int m = 0; m < 4; ++m)
    #pragma unroll
    for (int n = 0; n < 4; ++n) sc[m][n] = (f32x4)0.0f;
  #pragma unroll
  for (int m = 0; m < 4; ++m)
    #pragma unroll
    for (int n = 0; n < 4; ++n)
      sc[m][n] = __builtin_amdgcn_mfma_f32_16x16x32_bf16(kf[m], qf[n], sc[m][n], 0, 0, 0);

  const float scale = 0.1767766952966369f;
  #pragma unroll
  for (int n = 0; n < 4; ++n) {
    float mx = -1e30f;
    #pragma unroll
    for (int m = 0; m < 4; ++m)
      #pragma unroll
      for (int r = 0; r < 4; ++r) mx = fmaxf(mx, sc[m][n][r]);
    mx = fmaxf(mx, __shfl_xor(mx, 16, 64));
    mx = fmaxf(mx, __shfl_xor(mx, 32, 64));
    mx *= scale;
    float sum = 0.f;
    #pragma unroll
    for (int m = 0; m < 4; ++m)
      #pragma unroll
      for (int r = 0; r < 4; ++r) {
        float e = __expf(sc[m][n][r]*scale - mx);
        sc[m][n][r] = e; sum += e;
      }
    sum += __shfl_xor(sum, 16, 64);
    sum += __shfl_xor(sum, 32, 64);
    float inv = 1.0f / sum;
    #pragma unroll
    for (int m = 0; m < 4; ++m) {
      uint2 pk;
      pk.x = f2bfbits(sc[m][n][0]*inv) | (f2bfbits(sc[m][n][1]*inv) << 16);
      pk.y = f2bfbits(sc[m][n][2]*inv) | (f2bfbits(sc[m][n][3]*inv) << 16);
      *(uint2*)(P + (n*16+ln)*72 + m*16 + quad*4) = pk;
    }
  }

  bf16x8 pf[4][2];
  #pragma unroll
  for (int n = 0; n < 4; ++n)
    #pragma unroll
    for (int k = 0; k < 2; ++k)
      pf[n][k] = *(const bf16x8*)(P + (n*16+ln)*72 + k*32 + quad*8);

  f32x4 av[2][4], mc[4];
  #pragma unroll
  for (int n = 0; n < 4; ++n) { av[0][n] = (f32x4)0.0f; av[1][n] = (f32x4)0.0f; mc[n] = (f32x4)0.0f; }
  #pragma unroll
  for (int k = 0; k < 2; ++k) {
    bf16x8 va0 = *(const bf16x8*)(Vt  + (0  + ln)*72 + k*32 + quad*8);
    bf16x8 va1 = *(const bf16x8*)(Vt  + (16 + ln)*72 + k*32 + quad*8);
    bf16x8 ca  = *(const bf16x8*)(CEt + ln*72        + k*32 + quad*8);
    #pragma unroll
    for (int n = 0; n < 4; ++n) {
      av[0][n] = __builtin_amdgcn_mfma_f32_16x16x32_bf16(va0, pf[n][k], av[0][n], 0, 0, 0);
      av[1][n] = __builtin_amdgcn_mfma_f32_16x16x32_bf16(va1, pf[n][k], av[1][n], 0, 0, 0);
      mc[n]    = __builtin_amdgcn_mfma_f32_16x16x32_bf16(ca,  pf[n][k], mc[n],    0, 0, 0);
    }
  }

  #pragma unroll
  for (int n = 0; n < 4; ++n) {
    int i = n*16 + ln;
    int t = base + ((i >> 3) << 7) + (i & 7);
    unsigned short* ao = af + (size_t)t*256 + hs*32;
    #pragma unroll
    for (int m = 0; m < 2; ++m) {
      uint2 pk;
      pk.x = f2bfbits(av[m][n][0]) | (f2bfbits(av[m][n][1]) << 16);
      pk.y = f2bfbits(av[m][n][2]) | (f2bfbits(av[m][n][3]) << 16);
      *(uint2*)(ao + m*16 + quad*4) = pk;
    }
    float c0 = bfbits2f(CEt[(quad*4+0)*72 + i]);
    float c1 = bfbits2f(CEt[(quad*4+1)*72 + i]);
    float c2 = bfbits2f(CEt[(quad*4+2)*72 + i]);
    float c3 = bfbits2f(CEt[(quad*4+3)*72 + i]);
    uint2 pm;
    pm.x = f2bfbits(mc[n][0]-c0) | (f2bfbits(mc[n][1]-c1) << 16);
    pm.y = f2bfbits(mc[n][2]-c2) | (f2bfbits(mc[n][3]-c3) << 16);
    *(uint2*)(mdiff + (size_t)t*128 + hs*16 + quad*4) = pm;
  }
}

// ---- depthwise 3x3 SAME + bias + exact gelu, prefetched 4-row strips ----
// Block = 1024 channels of one column × one 4-row strip (32768 blocks).
// Interior strips: 18 unconditional loads into statically-indexed L[6][3],
// then compute. Column edges: clamp address + zero the edge weight taps.
// Row-edge strips (2/32): guarded load path.
__global__ __launch_bounds__(256) void k_conv(const unsigned short* __restrict__ h1,
    const float* __restrict__ Wdw, const float* __restrict__ bdw,
    unsigned short* __restrict__ h2) {
  const int blk = blockIdx.x;
  const int c  = blk & 127;              // column
  const int r0 = ((blk >> 7) & 31) << 2; // 4-row strip base
  const int b  = blk >> 12;              // batch
  const int gch = threadIdx.x << 2;      // 4 channels per thread

  const float4 zf = make_float4(0.f, 0.f, 0.f, 0.f);
  float4 w[3][3];
  #pragma unroll
  for (int kr = 0; kr < 3; ++kr)
    #pragma unroll
    for (int kc = 0; kc < 3; ++kc)
      w[kr][kc] = *(const float4*)(Wdw + (kr*3 + kc)*1024 + gch);
  // column-edge handling: zero the out-of-range taps, clamp the address
  if (c == 0)   { w[0][0] = zf; w[1][0] = zf; w[2][0] = zf; }
  if (c == 127) { w[0][2] = zf; w[1][2] = zf; w[2][2] = zf; }
  const int cm = (c > 0)   ? -1024 : 0;   // element offset to col c-1 (clamped)
  const int cp = (c < 127) ?  1024 : 0;   // element offset to col c+1 (clamped)

  // ---- prefetch 6 input rows × 3 cols, branch-free on the interior ----
  uint2 L[6][3];
  if (r0 > 0 && r0 < 124) {
    const unsigned short* p0 =
        h1 + (((size_t)(b*128 + (r0-1))*128 + c) << 10) + gch;
    #pragma unroll
    for (int rr = 0; rr < 6; ++rr) {
      const unsigned short* p = p0 + (size_t)rr * 131072;  // +1 row
      L[rr][0] = *(const uint2*)(p + cm);
      L[rr][1] = *(const uint2*)p;
      L[rr][2] = *(const uint2*)(p + cp);
    }
  } else {
    #pragma unroll
    for (int rr = 0; rr < 6; ++rr) {
      const int ir = r0 + rr - 1;
      if ((unsigned)ir <= 127u) {
        const unsigned short* p =
            h1 + (((size_t)(b*128 + ir)*128 + c) << 10) + gch;
        L[rr][0] = *(const uint2*)(p + cm);
        L[rr][1] = *(const uint2*)p;
        L[rr][2] = *(const uint2*)(p + cp);
      } else {
        L[rr][0] = make_uint2(0u, 0u);
        L[rr][1] = make_uint2(0u, 0u);
        L[rr][2] = make_uint2(0u, 0u);
      }
    }
  }

  // ---- compute: out row o (0..3) uses input rows rr = o+kr with tap w[kr] ----
  const float4 bb = *(const float4*)(bdw + gch);
  float4 acc[4];
  #pragma unroll
  for (int o = 0; o < 4; ++o) acc[o] = bb;

  #pragma unroll
  for (int rr = 0; rr < 6; ++rr) {
    float4 i0 = unpk4(L[rr][0]);
    float4 i1 = unpk4(L[rr][1]);
    float4 i2 = unpk4(L[rr][2]);
    #pragma unroll
    for (int kr = 0; kr < 3; ++kr) {
      const int o = rr - kr;
      if (o >= 0 && o <= 3) {
        fma4(acc[o], w[kr][0], i0);
        fma4(acc[o], w[kr][1], i1);
        fma4(acc[o], w[kr][2], i2);
      }
    }
  }

  const float kk = 0.70710678118654752440f;
  #pragma unroll
  for (int o = 0; o < 4; ++o) {
    float4 a = acc[o];
    a.x = 0.5f*a.x*(1.0f + erff(a.x*kk));
    a.y = 0.5f*a.y*(1.0f + erff(a.y*kk));
    a.z = 0.5f*a.z*(1.0f + erff(a.z*kk));
    a.w = 0.5f*a.w*(1.0f + erff(a.w*kk));
    uint2 out;
    out.x = f2bfbits(a.x) | (f2bfbits(a.y) << 16);
    out.y = f2bfbits(a.z) | (f2bfbits(a.w) << 16);
    *(uint2*)(h2 + (((size_t)(b*128 + r0 + o)*128 + c) << 10) + gch) = out;
  }
}

extern "C" void kernel_launch(void* const* d_in, const int* in_sizes, int n_in,
                              void* d_out, int out_size, void* d_ws, size_t ws_size,
                              hipStream_t stream) {
  const float* x     = (const float*)d_in[0];
  const float* cor   = (const float*)d_in[1];
  const float* g1    = (const float*)d_in[2];
  const float* b1    = (const float*)d_in[3];
  const float* Wq    = (const float*)d_in[4];
  const float* bq    = (const float*)d_in[5];
  const float* Wkv   = (const float*)d_in[6];
  const float* bkv   = (const float*)d_in[7];
  const float* Wproj = (const float*)d_in[8];
  const float* bproj = (const float*)d_in[9];
  const float* Wce   = (const float*)d_in[10];
  const float* bce   = (const float*)d_in[11];
  const float* Wmp   = (const float*)d_in[12];
  const float* bmp   = (const float*)d_in[13];
  const float* g2    = (const float*)d_in[14];
  const float* b2    = (const float*)d_in[15];
  const float* Wfc1  = (const float*)d_in[16];
  const float* bfc1  = (const float*)d_in[17];
  const float* Wdw   = (const float*)d_in[18];
  const float* bdw   = (const float*)d_in[19];
  const float* Wfc2  = (const float*)d_in[20];
  const float* bfc2  = (const float*)d_in[21];

  float* xout = (float*)d_out;
  float* mout = xout + (size_t)NTOK * 256;

  unsigned short* ws16   = (unsigned short*)d_ws;
  unsigned short* xnormb = ws16;                 // 33554432 el
  unsigned short* qb     = ws16 + 33554432;      // 33554432 el
  unsigned short* kvb    = ws16 + 67108864;      // 67108864 el
  unsigned short* afb    = ws16 + 134217728;     // 33554432 el
  unsigned short* mdiff  = ws16 + 167772160;     // 16777216 el
  unsigned short* xn2    = ws16 + 184549376;     // 33554432 el
  unsigned short* Wqt    = ws16 + 218103808;     // 65536
  unsigned short* Wkvt   = ws16 + 218169344;     // 131072
  unsigned short* Wprojt = ws16 + 218300416;     // 65536
  unsigned short* Wmpt   = ws16 + 218365952;     // 16384
  unsigned short* Wfc1t  = ws16 + 218382336;     // 262144 (ends 218644480)
  unsigned short* h1     = ws16;                 // 134217728 el
  unsigned short* h2     = ws16 + 134217728;     // 134217728 el
  unsigned short* Wfc2t  = ws16;                 // 262144 el (prepped after conv)

  k_wt<<<dim3(256, 1), 256, 0, stream>>>(Wq,    Wqt,    256, 256);
  k_wt<<<dim3(256, 2), 256, 0, stream>>>(Wkv,   Wkvt,   256, 512);
  k_wt<<<dim3(256, 1), 256, 0, stream>>>(Wproj, Wprojt, 256, 256);
  k_wt<<<dim3(128, 1), 256, 0, stream>>>(Wmp,   Wmpt,   128, 128);
  k_wt<<<dim3(256, 4), 256, 0, stream>>>(Wfc1,  Wfc1t,  256, 1024);
  k_ln1<<<dim3(NTOK/4), 256, 0, stream>>>(x, g1, b1, xnormb);

  k_gemm<0><<<dim3(1024, 2), 256, 0, stream>>>(xnormb, Wqt,  bq,  nullptr, nullptr, qb,  256, 256);
  k_gemm<0><<<dim3(1024, 4), 256, 0, stream>>>(xnormb, Wkvt, bkv, nullptr, nullptr, kvb, 256, 512);
  k_attn3<<<dim3(4096), 256, 0, stream>>>(qb, kvb, cor, Wce, bce, afb, mdiff);
  k_gemm<1><<<dim3(1024, 2), 256, 0, stream>>>(afb, Wprojt, bproj, xnormb, xout, nullptr, 256, 256);
  k_gemm<2><<<dim3(1024, 1), 256, 0, stream>>>(mdiff, Wmpt, bmp, nullptr, mout, nullptr, 128, 128);
  k_ln2<<<dim3(NTOK/4), 256, 0, stream>>>(xout, g2, b2, xn2);
  k_gemm<0><<<dim3(1024, 8), 256, 0, stream>>>(xn2, Wfc1t, bfc1, nullptr, nullptr, h1, 256, 1024);
  k_conv<<<dim3(32768), 256, 0, stream>>>(h1, Wdw, bdw, h2);
  k_wt<<<dim3(1024, 1), 256, 0, stream>>>(Wfc2, Wfc2t, 1024, 256);
  k_gemm<3><<<dim3(1024, 2), 256, 0, stream>>>(h2, Wfc2t, bfc2, nullptr, xout, nullptr, 1024, 256);
}